// Round 11
// baseline (769.811 us; speedup 1.0000x reference)
//
#include <hip/hip_runtime.h>
#include <hip/hip_bf16.h>
#include <stdint.h>

// Pipeline:
//   k_g1hopf: FUSED producer/consumer — blocks 0..63 run the Hopf chains,
//             blocks 64..2111 run gemm1 t-tiles; per-t-tile device-scope
//             flags (in d_out scratch) let hopf start as tiles land.
//   k_critic: value[t] = |c-linear(d1[t])|
//   k_ld    : lD1/lD2[t] = sigmoid(+-5*(value[t]-value[t-1]))
//   k_gemmD : M1r/M1i/M2r/M2i partials, K-split x4
//   k_epi   : reduce partials + lD scaling + bias + relu + noise + norm -> nrm
//   k_scan_part/mid/out : gpi = 0.01*cumsum(nrm), softmax, outputs
//
// Ledger (razor-margin test: passing absmax 1.25 vs threshold 1.27):
//   R3 hopf (reg ping-pong + saddr + cvt_pk + OCML sincos): 212us PASSED.
//     Issue-bound: ~62 instr/step x 2cy = 124 cy/step; OCML body is the
//     floor and numerics are BIT-FROZEN (R6/R7/R8 trig subs all failed).
//   R10 = R3 hopf + split scan: 576us total PASSED.
//   R11 (this): scheduling-only. hopf uses 64 waves (0.6% of machine) for
//     212us while gemm1 (~100us of fp32 VALU work) serialized before it.
//     Fuse with role-split blocks + producer-consumer flags:
//       producer block: __threadfence(); __syncthreads(); tid0
//         __hip_atomic_fetch_add(flags[t_tile], 1, RELEASE, AGENT)
//       consumer: spin __hip_atomic_load(ACQUIRE, AGENT) < 32 before the
//         first prefetch of each tile (prefetch runs 64 steps ahead).
//     FP op sequences byte-identical to R10 — only timing changes.
//     Flags = first 256B of d_out (workspace is full); zeroed by our own
//     hipMemsetAsync each launch; overwritten by k_scan_mid at the end.
//     No deadlock: 64 spinning hopf blocks hold <=64 CUs; gemm1 always
//     has >=192 CUs to progress through, any dispatch order.

#define T_ 4096
#define D_ 256
#define U_ 2048
#define A_ 64

__device__ __forceinline__ uint32_t pack2(float lo, float hi) {
  __hip_bfloat16 l = __float2bfloat16(lo);
  __hip_bfloat16 h = __float2bfloat16(hi);
  uint16_t lu, hu;
  __builtin_memcpy(&lu, &l, 2);
  __builtin_memcpy(&hu, &h, 2);
  return (uint32_t)lu | ((uint32_t)hu << 16);
}
__device__ __forceinline__ float bflo(uint32_t p) { return __uint_as_float(p << 16); }
__device__ __forceinline__ float bfhi(uint32_t p) { return __uint_as_float(p & 0xffff0000u); }

// ---------------- Hopf step/load macros (R3 structure, PROVEN) -----------
#define HOPF_LOAD(BUF, i, tbase)                                            \
  do {                                                                      \
    const float* bx_ = xc + (size_t)((tbase) + (i)) * (U_ * 2);             \
    asm volatile("global_load_dwordx2 %0, %1, %2"                           \
                 : "=v"(BUF[i])                                             \
                 : "v"(voffx), "s"(bx_));                                   \
  } while (0)

#define HOPF_STEP(BUF, i, tb)                                               \
  do {                                                                      \
    const float xr_ = BUF[i].x, xi_ = BUF[i].y;                             \
    const float f_ = fmaf(xr_, c, xi_ * s);                                 \
    const float g_ = fmaf(xi_, c, -(xr_ * s));                              \
    const float rn_ = fmaf(0.01f, fmaf(r, fmaf(-r, r, 1.0f), f_), r);       \
    const float rinv_ = __builtin_amdgcn_rcpf(fmaxf(r, 1e-6f));             \
    const float phin_ = fmaf(0.01f, g_ * rinv_, phi + dto);                 \
    float cn_, sn_;                                                         \
    __sincosf(phin_, &sn_, &cn_);                                           \
    uint32_t pk_;                                                           \
    asm("v_cvt_pk_bf16_f32 %0, %1, %2"                                     \
        : "=v"(pk_)                                                         \
        : "v"(rn_ * cn_), "v"(rn_ * sn_));                                  \
    const uint32_t* bd_ = dst + (size_t)((tb) + (i)) * U_;                  \
    asm volatile("global_store_dword %0, %1, %2" ::"v"(voffd), "v"(pk_),    \
                 "s"(bd_));                                                  \
    r = rn_; phi = phin_; c = cn_; s = sn_;                                 \
  } while (0)

#define VMWAIT(N)                                  \
  asm volatile("s_waitcnt vmcnt(" #N ")");         \
  __builtin_amdgcn_sched_barrier(0)

// consumer-side tile gate (acquire, device scope); prefetch runs 64 steps
// ahead of consume so in steady state this is one satisfied load per iter.
#define WAIT_TILE(tt)                                                       \
  do {                                                                      \
    while (__hip_atomic_load(&flags[tt], __ATOMIC_ACQUIRE,                  \
                             __HIP_MEMORY_SCOPE_AGENT) < 32u)               \
      __builtin_amdgcn_s_sleep(2);                                          \
    __builtin_amdgcn_sched_barrier(0);                                      \
  } while (0)

// ---------------- FUSED gemm1 + hopf ----------------
// grid 2112 x 256: blocks 0..63 hopf (threads 0..63 active), 64..2111 gemm1.
// gemm1 tile map: gb = bid-64; t_tile = gb>>5, u_tile = gb&31  (u fastest,
// so in-order dispatch completes t-tiles in ascending order).
__global__ __launch_bounds__(256) void k_g1hopf(
    const float* __restrict__ S, const float* __restrict__ Wr,
    const float* __restrict__ Wi, const float* __restrict__ br,
    const float* __restrict__ bi, const float* __restrict__ phi1,
    const float* __restrict__ phi2, const float* __restrict__ om1,
    const float* __restrict__ om2, float* __restrict__ xc,
    uint32_t* __restrict__ d1c, uint32_t* __restrict__ d2c,
    uint32_t* __restrict__ flags) {
  const int bid = blockIdx.x;
  if (bid >= 64) {
    // ================= gemm1 role (NUMERICS FROZEN, byte-identical) =====
    __shared__ float sT[32][68];
    __shared__ float wrT[32][68];
    __shared__ float wiT[32][68];
    const int tid = threadIdx.x;
    const int gb = bid - 64;
    const int t0 = (gb >> 5) * 64;
    const int u0 = (gb & 31) * 64;
    const int un = tid & 15, tm = tid >> 4;
    const int lr = tid >> 3;        // 0..31
    const int lc = (tid & 7) * 4;   // 0..28
    float accR[4][4] = {}, accI[4][4] = {};
    for (int k0 = 0; k0 < D_; k0 += 32) {
      __syncthreads();
#pragma unroll
      for (int p = 0; p < 2; ++p) {
        const int row = p * 32 + lr;
        float4 v = *(const float4*)&S[(size_t)(t0 + row) * D_ + k0 + lc];
        sT[lc + 0][row] = v.x; sT[lc + 1][row] = v.y;
        sT[lc + 2][row] = v.z; sT[lc + 3][row] = v.w;
        float4 a = *(const float4*)&Wr[(size_t)(u0 + row) * D_ + k0 + lc];
        wrT[lc + 0][row] = a.x; wrT[lc + 1][row] = a.y;
        wrT[lc + 2][row] = a.z; wrT[lc + 3][row] = a.w;
        float4 b = *(const float4*)&Wi[(size_t)(u0 + row) * D_ + k0 + lc];
        wiT[lc + 0][row] = b.x; wiT[lc + 1][row] = b.y;
        wiT[lc + 2][row] = b.z; wiT[lc + 3][row] = b.w;
      }
      __syncthreads();
#pragma unroll
      for (int k = 0; k < 32; ++k) {
        const float4 sv = *(const float4*)&sT[k][tm * 4];
        const float4 ar = *(const float4*)&wrT[k][un * 4];
        const float4 ai = *(const float4*)&wiT[k][un * 4];
        const float ss[4] = {sv.x, sv.y, sv.z, sv.w};
        const float wd[4] = {ar.x - ai.x, ar.y - ai.y, ar.z - ai.z, ar.w - ai.w};
        const float wm[4] = {ar.x + ai.x, ar.y + ai.y, ar.z + ai.z, ar.w + ai.w};
#pragma unroll
        for (int i = 0; i < 4; ++i)
#pragma unroll
          for (int j = 0; j < 4; ++j) {
            accR[i][j] = fmaf(ss[i], wd[j], accR[i][j]);
            accI[i][j] = fmaf(ss[i], wm[j], accI[i][j]);
          }
      }
    }
    const float4 brv = *(const float4*)&br[u0 + un * 4];
    const float4 biv = *(const float4*)&bi[u0 + un * 4];
    const float brx[4] = {brv.x, brv.y, brv.z, brv.w};
    const float bix[4] = {biv.x, biv.y, biv.z, biv.w};
#pragma unroll
    for (int i = 0; i < 4; ++i) {
      float vr[4], vi[4];
#pragma unroll
      for (int j = 0; j < 4; ++j) {
        vr[j] = fmaxf(accR[i][j] + brx[j], 0.f);
        vi[j] = fmaxf(accI[i][j] + bix[j], 0.f);
      }
      const size_t base = ((size_t)(t0 + tm * 4 + i) * U_ + u0 + un * 4) * 2;
      *(float4*)&xc[base + 0] = make_float4(vr[0], vi[0], vr[1], vi[1]);
      *(float4*)&xc[base + 4] = make_float4(vr[2], vi[2], vr[3], vi[3]);
    }
    // publish this tile: agent-visible release, one count per u-block
    __threadfence();
    __syncthreads();
    if (tid == 0)
      __hip_atomic_fetch_add(&flags[t0 >> 6], 1u, __ATOMIC_RELEASE,
                             __HIP_MEMORY_SCOPE_AGENT);
    return;
  }
  // ================= hopf role (R3 structure, PROVEN) ===================
  if (threadIdx.x >= 64) return;  // 1 wave per block; no barriers below
  const int ub = bid & 31;
  const int osc = bid >> 5;
  const int u = ub * 64 + threadIdx.x;
  float phi = (osc ? phi2[u] : phi1[u]) * 0.1f;
  const float omega = osc ? om2[u] : om1[u];
  const uint32_t* __restrict__ dst = (osc ? d2c : d1c);
  const float dto = 0.01f * omega;
  float r = 1.0f;
  float c, s;
  __sincosf(phi, &s, &c);
  const uint32_t voffx = (uint32_t)u * 8u;  // byte offset into xc rows
  const uint32_t voffd = (uint32_t)u * 4u;  // byte offset into d rows

  constexpr int PF = 32;
  float2 bufA[PF], bufB[PF];
  // Prologue: rows 0..63 = tile 0; gate, then stage both groups.
  WAIT_TILE(0);
#pragma unroll
  for (int i = 0; i < PF; ++i) HOPF_LOAD(bufA, i, 0);
#pragma unroll
  for (int i = 0; i < PF; ++i) HOPF_LOAD(bufB, i, PF);
  VMWAIT(32);

  for (int t0 = 0; t0 < T_; t0 += 2 * PF) {
    // consume A (t0..t0+31): 32 stores
#pragma unroll
    for (int i = 0; i < PF; ++i) HOPF_STEP(bufA, i, t0);
    // gate + prefetch A <- t0+64 (tile t0/64+1; dummy wrap on tail)
    {
      int tp = t0 + 2 * PF;
      if (tp >= T_) tp = 0;
      WAIT_TILE(tp >> 6);  // acquire-load drains vmcnt; invariants re-derived
#pragma unroll
      for (int i = 0; i < PF; ++i) HOPF_LOAD(bufA, i, tp);
    }
    VMWAIT(63);
    // consume B (t0+32..t0+63)
#pragma unroll
    for (int i = 0; i < PF; ++i) HOPF_STEP(bufB, i, t0 + PF);
    // prefetch B <- t0+96 (same tile as A's prefetch; already gated)
    {
      int tp = t0 + 3 * PF;
      if (tp >= T_) tp = 0;
#pragma unroll
      for (int i = 0; i < PF; ++i) HOPF_LOAD(bufB, i, tp);
    }
    VMWAIT(63);
  }
  asm volatile("s_waitcnt vmcnt(0)");  // drain asm stores before endpgm
}

// ---------------- Critic: value[t] ----------------
__global__ __launch_bounds__(256) void k_critic(
    const uint32_t* __restrict__ d1c, const float* __restrict__ cWr,
    const float* __restrict__ cWi, const float* __restrict__ cbr,
    const float* __restrict__ cbi, float* __restrict__ value) {
  const int t = blockIdx.x;
  const int tid = threadIdx.x;
  float vr = 0.f, vi = 0.f;
#pragma unroll
  for (int i = 0; i < 8; ++i) {
    const int uu = i * 256 + tid;
    const uint32_t p = d1c[(size_t)t * U_ + uu];
    const float dr = bflo(p), di = bfhi(p);
    const float wr = cWr[uu], wi = cWi[uu];
    vr = fmaf(dr, wr, fmaf(-di, wi, vr));
    vi = fmaf(dr, wi, fmaf(di, wr, vi));
  }
#pragma unroll
  for (int o = 32; o >= 1; o >>= 1) {
    vr += __shfl_xor(vr, o);
    vi += __shfl_xor(vi, o);
  }
  __shared__ float red[2][4];
  if ((tid & 63) == 0) { red[0][tid >> 6] = vr; red[1][tid >> 6] = vi; }
  __syncthreads();
  if (tid == 0) {
    const float r0 = red[0][0] + red[0][1] + red[0][2] + red[0][3] + cbr[0];
    const float i0 = red[1][0] + red[1][1] + red[1][2] + red[1][3] + cbi[0];
    value[t] = sqrtf(r0 * r0 + i0 * i0);
  }
}

// ---------------- lD1/lD2 ----------------
__global__ __launch_bounds__(256) void k_ld(const float* __restrict__ value,
                                            float* __restrict__ lD1,
                                            float* __restrict__ lD2) {
  const int t = blockIdx.x * 256 + threadIdx.x;
  const float v = value[t];
  const float pv = (t > 0) ? value[t - 1] : 0.f;
  const float x = 5.0f * (v - pv);
  const float sg = 1.0f / (1.0f + __expf(-x));
  lD1[t] = sg;
  lD2[t] = 1.0f - sg;
}

// ---------------- Phase-D GEMMs (K-split x4) ----------------
// tile 64t x 64a, 256 threads, thread 4t x 4a x 4 mats; K chunk 32.
__global__ __launch_bounds__(256) void k_gemmD(
    const uint32_t* __restrict__ d1c, const uint32_t* __restrict__ d2c,
    const float* __restrict__ dpWr, const float* __restrict__ dpWi,
    const float* __restrict__ ipWr, const float* __restrict__ ipWi,
    float* __restrict__ mpart) {
  __shared__ uint32_t d1T[32][68];
  __shared__ uint32_t d2T[32][68];
  __shared__ float w1r[32][68], w1i[32][68], w2r[32][68], w2i[32][68];
  const int tid = threadIdx.x;
  const int t0 = blockIdx.x * 64;
  const int ks = blockIdx.y;
  const int kb = ks * 512;
  const int an = tid & 15, tm = tid >> 4;
  const int lr = tid >> 3, lc = (tid & 7) * 4;
  float a1r[4][4] = {}, a1i[4][4] = {}, a2r[4][4] = {}, a2i[4][4] = {};
  for (int kc = 0; kc < 512; kc += 32) {
    __syncthreads();
#pragma unroll
    for (int p = 0; p < 2; ++p) {
      const int row = p * 32 + lr;
      const int col = kb + kc + lc;
      uint4 v1 = *(const uint4*)&d1c[(size_t)(t0 + row) * U_ + col];
      d1T[lc + 0][row] = v1.x; d1T[lc + 1][row] = v1.y;
      d1T[lc + 2][row] = v1.z; d1T[lc + 3][row] = v1.w;
      uint4 v2 = *(const uint4*)&d2c[(size_t)(t0 + row) * U_ + col];
      d2T[lc + 0][row] = v2.x; d2T[lc + 1][row] = v2.y;
      d2T[lc + 2][row] = v2.z; d2T[lc + 3][row] = v2.w;
      float4 f;
      f = *(const float4*)&dpWr[(size_t)row * U_ + col];
      w1r[lc + 0][row] = f.x; w1r[lc + 1][row] = f.y;
      w1r[lc + 2][row] = f.z; w1r[lc + 3][row] = f.w;
      f = *(const float4*)&dpWi[(size_t)row * U_ + col];
      w1i[lc + 0][row] = f.x; w1i[lc + 1][row] = f.y;
      w1i[lc + 2][row] = f.z; w1i[lc + 3][row] = f.w;
      f = *(const float4*)&ipWr[(size_t)row * U_ + col];
      w2r[lc + 0][row] = f.x; w2r[lc + 1][row] = f.y;
      w2r[lc + 2][row] = f.z; w2r[lc + 3][row] = f.w;
      f = *(const float4*)&ipWi[(size_t)row * U_ + col];
      w2i[lc + 0][row] = f.x; w2i[lc + 1][row] = f.y;
      w2i[lc + 2][row] = f.z; w2i[lc + 3][row] = f.w;
    }
    __syncthreads();
#pragma unroll
    for (int k = 0; k < 32; ++k) {
      const uint4 p1 = *(const uint4*)&d1T[k][tm * 4];
      const uint4 p2 = *(const uint4*)&d2T[k][tm * 4];
      const float4 q1r = *(const float4*)&w1r[k][an * 4];
      const float4 q1i = *(const float4*)&w1i[k][an * 4];
      const float4 q2r = *(const float4*)&w2r[k][an * 4];
      const float4 q2i = *(const float4*)&w2i[k][an * 4];
      const float d1r_[4] = {bflo(p1.x), bflo(p1.y), bflo(p1.z), bflo(p1.w)};
      const float d1i_[4] = {bfhi(p1.x), bfhi(p1.y), bfhi(p1.z), bfhi(p1.w)};
      const float d2r_[4] = {bflo(p2.x), bflo(p2.y), bflo(p2.z), bflo(p2.w)};
      const float d2i_[4] = {bfhi(p2.x), bfhi(p2.y), bfhi(p2.z), bfhi(p2.w)};
      const float u1r[4] = {q1r.x, q1r.y, q1r.z, q1r.w};
      const float u1i[4] = {q1i.x, q1i.y, q1i.z, q1i.w};
      const float u2r[4] = {q2r.x, q2r.y, q2r.z, q2r.w};
      const float u2i[4] = {q2i.x, q2i.y, q2i.z, q2i.w};
#pragma unroll
      for (int i = 0; i < 4; ++i)
#pragma unroll
        for (int j = 0; j < 4; ++j) {
          a1r[i][j] = fmaf(d1r_[i], u1r[j], fmaf(-d1i_[i], u1i[j], a1r[i][j]));
          a1i[i][j] = fmaf(d1r_[i], u1i[j], fmaf(d1i_[i], u1r[j], a1i[i][j]));
          a2r[i][j] = fmaf(d2r_[i], u2r[j], fmaf(-d2i_[i], u2i[j], a2r[i][j]));
          a2i[i][j] = fmaf(d2r_[i], u2i[j], fmaf(d2i_[i], u2r[j], a2i[i][j]));
        }
    }
  }
  const size_t MS = (size_t)T_ * A_;
#pragma unroll
  for (int i = 0; i < 4; ++i) {
    const size_t base = (size_t)(t0 + tm * 4 + i) * A_ + an * 4;
    *(float4*)&mpart[(size_t)(0 * 4 + ks) * MS + base] =
        make_float4(a1r[i][0], a1r[i][1], a1r[i][2], a1r[i][3]);
    *(float4*)&mpart[(size_t)(1 * 4 + ks) * MS + base] =
        make_float4(a1i[i][0], a1i[i][1], a1i[i][2], a1i[i][3]);
    *(float4*)&mpart[(size_t)(2 * 4 + ks) * MS + base] =
        make_float4(a2r[i][0], a2r[i][1], a2r[i][2], a2r[i][3]);
    *(float4*)&mpart[(size_t)(3 * 4 + ks) * MS + base] =
        make_float4(a2i[i][0], a2i[i][1], a2i[i][2], a2i[i][3]);
  }
}

// ---------------- Epilogue: partial-reduce + norm ----------------
__global__ __launch_bounds__(256) void k_epi(
    const float* __restrict__ mpart, const float* __restrict__ lD1,
    const float* __restrict__ lD2, const float* __restrict__ noise,
    const float* __restrict__ dpbr, const float* __restrict__ dpbi,
    const float* __restrict__ ipbr, const float* __restrict__ ipbi,
    float* __restrict__ nrm) {
  const size_t MS = (size_t)T_ * A_;
  const int gid = blockIdx.x * 256 + threadIdx.x;
  const size_t e0 = (size_t)gid * 4;
  const int t = (int)(e0 >> 6);
  const int a0 = (int)(e0 & 63);
  float m[4][4];
#pragma unroll
  for (int mi = 0; mi < 4; ++mi) {
    float4 acc = *(const float4*)&mpart[(size_t)(mi * 4 + 0) * MS + e0];
#pragma unroll
    for (int ksi = 1; ksi < 4; ++ksi) {
      const float4 v = *(const float4*)&mpart[(size_t)(mi * 4 + ksi) * MS + e0];
      acc.x += v.x; acc.y += v.y; acc.z += v.z; acc.w += v.w;
    }
    m[mi][0] = acc.x; m[mi][1] = acc.y; m[mi][2] = acc.z; m[mi][3] = acc.w;
  }
  const float l1 = lD1[t], l2 = lD2[t];
  const float4 nzv = *(const float4*)&noise[e0];
  const float nz[4] = {nzv.x, nzv.y, nzv.z, nzv.w};
  const float4 q1 = *(const float4*)&dpbr[a0];
  const float4 q2 = *(const float4*)&dpbi[a0];
  const float4 q3 = *(const float4*)&ipbr[a0];
  const float4 q4 = *(const float4*)&ipbi[a0];
  const float b1r[4] = {q1.x, q1.y, q1.z, q1.w};
  const float b1i[4] = {q2.x, q2.y, q2.z, q2.w};
  const float b2r[4] = {q3.x, q3.y, q3.z, q3.w};
  const float b2i[4] = {q4.x, q4.y, q4.z, q4.w};
  float res[4];
#pragma unroll
  for (int j = 0; j < 4; ++j) {
    const float dpr = fmaxf(fmaf(l1, m[0][j], b1r[j]), 0.f);
    const float dpi = fmaxf(fmaf(l1, m[1][j], b1i[j]), 0.f);
    const float ipr = fmaxf(fmaf(l2, m[2][j], b2r[j]), 0.f);
    const float ipi = fmaxf(fmaf(l2, m[3][j], b2i[j]), 0.f);
    const float nzs = l2 * (2.f * nz[j] - 1.f);
    const float dr = dpr - ipr - nzs;
    const float di = dpi - ipi;
    res[j] = sqrtf(dr * dr + di * di);
  }
  *(float4*)&nrm[e0] = make_float4(res[0], res[1], res[2], res[3]);
}

// ---------------- Scan + softmax + outputs (parallel, 3 kernels) ----------
// chunk = 64 t-steps; 64 chunks. (Summation order proven passing.)
__global__ __launch_bounds__(64) void k_scan_part(const float* __restrict__ nrm,
                                                  float* __restrict__ csum) {
  const int c = blockIdx.x;
  const int a = threadIdx.x;
  const int tb = c * 64;
  float run = 0.f;
  for (int i = 0; i < 64; ++i) run += nrm[(size_t)(tb + i) * 64 + a];
  csum[c * 64 + a] = run;
}

__global__ __launch_bounds__(64) void k_scan_mid(const float* __restrict__ csum,
                                                 const float* __restrict__ value,
                                                 float* __restrict__ coff,
                                                 float* __restrict__ out) {
  const int a = threadIdx.x;
  float acc = 0.f;
#pragma unroll
  for (int cc = 0; cc < 64; ++cc) {
    coff[cc * 64 + a] = acc;
    acc += csum[cc * 64 + a];
  }
  const float g = 0.01f * acc;
  float mx = g;
#pragma unroll
  for (int o = 32; o >= 1; o >>= 1) mx = fmaxf(mx, __shfl_xor(mx, o));
  const float e = __expf(g - mx);
  float sm = e;
#pragma unroll
  for (int o = 32; o >= 1; o >>= 1) sm += __shfl_xor(sm, o);
  out[a] = e / sm;
  if (a == 0) out[64] = value[T_ - 1];
}

__global__ __launch_bounds__(64) void k_scan_out(const float* __restrict__ nrm,
                                                 const float* __restrict__ coff,
                                                 float* __restrict__ out) {
  const int c = blockIdx.x;
  const int a = threadIdx.x;
  const int tb = c * 64;
  float off = coff[c * 64 + a];
  float* o65 = out + 65;
  for (int i = 0; i < 64; ++i) {
    off += nrm[(size_t)(tb + i) * 64 + a];
    o65[(size_t)(tb + i) * 64 + a] = 0.01f * off;
  }
}

extern "C" void kernel_launch(void* const* d_in, const int* in_sizes, int n_in,
                              void* d_out, int out_size, void* d_ws,
                              size_t ws_size, hipStream_t stream) {
  const float* state = (const float*)d_in[0];
  const float* phi1 = (const float*)d_in[1];
  const float* phi2 = (const float*)d_in[2];
  const float* noise = (const float*)d_in[3];
  const float* om1 = (const float*)d_in[4];
  const float* om2 = (const float*)d_in[5];
  const float* l1Wr = (const float*)d_in[6];
  const float* l1Wi = (const float*)d_in[7];
  const float* l1br = (const float*)d_in[8];
  const float* l1bi = (const float*)d_in[9];
  const float* dpWr = (const float*)d_in[10];
  const float* dpWi = (const float*)d_in[11];
  const float* dpbr = (const float*)d_in[12];
  const float* dpbi = (const float*)d_in[13];
  const float* ipWr = (const float*)d_in[14];
  const float* ipWi = (const float*)d_in[15];
  const float* ipbr = (const float*)d_in[16];
  const float* ipbi = (const float*)d_in[17];
  const float* cWr = (const float*)d_in[18];
  const float* cWi = (const float*)d_in[19];
  const float* cbr = (const float*)d_in[20];
  const float* cbi = (const float*)d_in[21];
  float* out = (float*)d_out;

  // Workspace layout (overlapped; 128 MB total):
  //   [0,64M)   xc plane (fp32 r,i interleaved) -- dead after fused; reused
  //   [64M,96M) d1c (bf16 pairs)
  //   [96M,128M) d2c (bf16 pairs)
  //   reuse of [0,64M) after fused kernel:
  //     [0,16M)        mpart
  //     [16M,17M)      nrm
  //     [17M, +16K)    value
  //     [17M+16K..]    lD1, lD2, csum, coff
  // flags: first 256B of d_out (zeroed below; overwritten by k_scan_mid).
  char* ws = (char*)d_ws;
  float* xc = (float*)(ws + (size_t)0);
  uint32_t* d1c = (uint32_t*)(ws + (size_t)67108864);
  uint32_t* d2c = (uint32_t*)(ws + (size_t)100663296);
  float* mpart = (float*)(ws + (size_t)0);
  float* nrm = (float*)(ws + (size_t)16777216);
  float* value = (float*)(ws + (size_t)17825792);
  float* lD1 = (float*)(ws + (size_t)17825792 + 16384);
  float* lD2 = (float*)(ws + (size_t)17825792 + 32768);
  float* csum = (float*)(ws + (size_t)17825792 + 49152);
  float* coff = (float*)(ws + (size_t)17825792 + 65536);
  uint32_t* flags = (uint32_t*)out;

  hipMemsetAsync(out, 0, 256, stream);  // zero tile flags (stream-ordered)
  k_g1hopf<<<64 + (T_ / 64) * (U_ / 64), 256, 0, stream>>>(
      state, l1Wr, l1Wi, l1br, l1bi, phi1, phi2, om1, om2, xc, d1c, d2c,
      flags);
  k_critic<<<T_, 256, 0, stream>>>(d1c, cWr, cWi, cbr, cbi, value);
  k_ld<<<T_ / 256, 256, 0, stream>>>(value, lD1, lD2);
  k_gemmD<<<dim3(T_ / 64, 4), 256, 0, stream>>>(d1c, d2c, dpWr, dpWi, ipWr,
                                                ipWi, mpart);
  k_epi<<<256, 256, 0, stream>>>(mpart, lD1, lD2, noise, dpbr, dpbi, ipbr,
                                 ipbi, nrm);
  k_scan_part<<<64, 64, 0, stream>>>(nrm, csum);
  k_scan_mid<<<1, 64, 0, stream>>>(csum, value, coff, out);
  k_scan_out<<<64, 64, 0, stream>>>(nrm, coff, out);
}

// Round 12
// 740.722 us; speedup vs baseline: 1.0393x; 1.0393x over previous
//
#include <hip/hip_runtime.h>
#include <hip/hip_bf16.h>
#include <stdint.h>

// Pipeline:
//   k_g1hopf: FUSED producer/consumer — blocks 0..63 run the Hopf chains,
//             blocks 64..2111 run gemm1 t-tiles; per-t-tile device-scope
//             flags (in d_out scratch) let hopf start as tiles land.
//   k_critic: value[t] = |c-linear(d1[t])|
//   k_ld    : lD1/lD2[t] = sigmoid(+-5*(value[t]-value[t-1]))
//   k_gemmD : M1r/M1i/M2r/M2i partials, K-split x4
//   k_epi   : reduce partials + lD scaling + bias + relu + noise + norm -> nrm
//   k_scan_part/mid/out : gpi = 0.01*cumsum(nrm), softmax, outputs
//
// Ledger (razor-margin test: passing absmax 1.25 vs threshold 1.27):
//   R3 hopf: 212us PASSED; numerics BIT-FROZEN on gemm1->hopf path
//     (R6/R7/R8 trig substitutions all failed the margin).
//   R10 = serial gemm1+hopf + split scan: 576us PASSED.
//   R11 fusion v1: PASSED 1.25 (protocol sound) but 578us fused kernel:
//     (a) per-iteration ACQUIRE poll emitted buffer_inv + vmcnt(0) drain
//         (L1 poisoning + pipeline serialization, ~260us);
//     (b) hopf wave shared SIMD issue slots 1:N with gemm1 waves.
//   R12 (this): same protocol, two targeted fixes:
//     (a) poll via RELAXED __hip_atomic_fetch_add(&flag,0) — RMW executes
//         at the coherent point (livelock-proof), NO acquire cache-inv ops.
//         Data visibility is structural: producer __threadfence + RELEASE
//         add; consumer xc loads are FIRST-TOUCH (no stale line possible).
//     (b) s_setprio(3) on hopf waves — serial chain wins contested issue
//         slots; gemm1 fills its dependency-stall cycles (T5 mechanism).
//   FP op sequences byte-identical to R10.

#define T_ 4096
#define D_ 256
#define U_ 2048
#define A_ 64

__device__ __forceinline__ uint32_t pack2(float lo, float hi) {
  __hip_bfloat16 l = __float2bfloat16(lo);
  __hip_bfloat16 h = __float2bfloat16(hi);
  uint16_t lu, hu;
  __builtin_memcpy(&lu, &l, 2);
  __builtin_memcpy(&hu, &h, 2);
  return (uint32_t)lu | ((uint32_t)hu << 16);
}
__device__ __forceinline__ float bflo(uint32_t p) { return __uint_as_float(p << 16); }
__device__ __forceinline__ float bfhi(uint32_t p) { return __uint_as_float(p & 0xffff0000u); }

// ---------------- Hopf step/load macros (R3 structure, PROVEN) -----------
#define HOPF_LOAD(BUF, i, tbase)                                            \
  do {                                                                      \
    const float* bx_ = xc + (size_t)((tbase) + (i)) * (U_ * 2);             \
    asm volatile("global_load_dwordx2 %0, %1, %2"                           \
                 : "=v"(BUF[i])                                             \
                 : "v"(voffx), "s"(bx_));                                   \
  } while (0)

#define HOPF_STEP(BUF, i, tb)                                               \
  do {                                                                      \
    const float xr_ = BUF[i].x, xi_ = BUF[i].y;                             \
    const float f_ = fmaf(xr_, c, xi_ * s);                                 \
    const float g_ = fmaf(xi_, c, -(xr_ * s));                              \
    const float rn_ = fmaf(0.01f, fmaf(r, fmaf(-r, r, 1.0f), f_), r);       \
    const float rinv_ = __builtin_amdgcn_rcpf(fmaxf(r, 1e-6f));             \
    const float phin_ = fmaf(0.01f, g_ * rinv_, phi + dto);                 \
    float cn_, sn_;                                                         \
    __sincosf(phin_, &sn_, &cn_);                                           \
    uint32_t pk_;                                                           \
    asm("v_cvt_pk_bf16_f32 %0, %1, %2"                                     \
        : "=v"(pk_)                                                         \
        : "v"(rn_ * cn_), "v"(rn_ * sn_));                                  \
    const uint32_t* bd_ = dst + (size_t)((tb) + (i)) * U_;                  \
    asm volatile("global_store_dword %0, %1, %2" ::"v"(voffd), "v"(pk_),    \
                 "s"(bd_));                                                  \
    r = rn_; phi = phin_; c = cn_; s = sn_;                                 \
  } while (0)

#define VMWAIT(N)                                  \
  asm volatile("s_waitcnt vmcnt(" #N ")");         \
  __builtin_amdgcn_sched_barrier(0)

// consumer-side tile gate: RELAXED RMW poll (coherent-point read, no
// acquire cache-inv). Prefetch runs 64 steps ahead of consume, so in
// steady state this is one satisfied RMW per iteration.
#define WAIT_TILE(tt)                                                       \
  do {                                                                      \
    while (__hip_atomic_fetch_add(&flags[tt], 0u, __ATOMIC_RELAXED,         \
                                  __HIP_MEMORY_SCOPE_AGENT) < 32u)          \
      __builtin_amdgcn_s_sleep(8);                                          \
    __builtin_amdgcn_sched_barrier(0);                                      \
  } while (0)

// ---------------- FUSED gemm1 + hopf ----------------
// grid 2112 x 256: blocks 0..63 hopf (threads 0..63 active), 64..2111 gemm1.
// gemm1 tile map: gb = bid-64; t_tile = gb>>5, u_tile = gb&31  (u fastest,
// so in-order dispatch completes t-tiles in ascending order).
__global__ __launch_bounds__(256) void k_g1hopf(
    const float* __restrict__ S, const float* __restrict__ Wr,
    const float* __restrict__ Wi, const float* __restrict__ br,
    const float* __restrict__ bi, const float* __restrict__ phi1,
    const float* __restrict__ phi2, const float* __restrict__ om1,
    const float* __restrict__ om2, float* __restrict__ xc,
    uint32_t* __restrict__ d1c, uint32_t* __restrict__ d2c,
    uint32_t* __restrict__ flags) {
  const int bid = blockIdx.x;
  if (bid >= 64) {
    // ================= gemm1 role (NUMERICS FROZEN, byte-identical) =====
    __shared__ float sT[32][68];
    __shared__ float wrT[32][68];
    __shared__ float wiT[32][68];
    const int tid = threadIdx.x;
    const int gb = bid - 64;
    const int t0 = (gb >> 5) * 64;
    const int u0 = (gb & 31) * 64;
    const int un = tid & 15, tm = tid >> 4;
    const int lr = tid >> 3;        // 0..31
    const int lc = (tid & 7) * 4;   // 0..28
    float accR[4][4] = {}, accI[4][4] = {};
    for (int k0 = 0; k0 < D_; k0 += 32) {
      __syncthreads();
#pragma unroll
      for (int p = 0; p < 2; ++p) {
        const int row = p * 32 + lr;
        float4 v = *(const float4*)&S[(size_t)(t0 + row) * D_ + k0 + lc];
        sT[lc + 0][row] = v.x; sT[lc + 1][row] = v.y;
        sT[lc + 2][row] = v.z; sT[lc + 3][row] = v.w;
        float4 a = *(const float4*)&Wr[(size_t)(u0 + row) * D_ + k0 + lc];
        wrT[lc + 0][row] = a.x; wrT[lc + 1][row] = a.y;
        wrT[lc + 2][row] = a.z; wrT[lc + 3][row] = a.w;
        float4 b = *(const float4*)&Wi[(size_t)(u0 + row) * D_ + k0 + lc];
        wiT[lc + 0][row] = b.x; wiT[lc + 1][row] = b.y;
        wiT[lc + 2][row] = b.z; wiT[lc + 3][row] = b.w;
      }
      __syncthreads();
#pragma unroll
      for (int k = 0; k < 32; ++k) {
        const float4 sv = *(const float4*)&sT[k][tm * 4];
        const float4 ar = *(const float4*)&wrT[k][un * 4];
        const float4 ai = *(const float4*)&wiT[k][un * 4];
        const float ss[4] = {sv.x, sv.y, sv.z, sv.w};
        const float wd[4] = {ar.x - ai.x, ar.y - ai.y, ar.z - ai.z, ar.w - ai.w};
        const float wm[4] = {ar.x + ai.x, ar.y + ai.y, ar.z + ai.z, ar.w + ai.w};
#pragma unroll
        for (int i = 0; i < 4; ++i)
#pragma unroll
          for (int j = 0; j < 4; ++j) {
            accR[i][j] = fmaf(ss[i], wd[j], accR[i][j]);
            accI[i][j] = fmaf(ss[i], wm[j], accI[i][j]);
          }
      }
    }
    const float4 brv = *(const float4*)&br[u0 + un * 4];
    const float4 biv = *(const float4*)&bi[u0 + un * 4];
    const float brx[4] = {brv.x, brv.y, brv.z, brv.w};
    const float bix[4] = {biv.x, biv.y, biv.z, biv.w};
#pragma unroll
    for (int i = 0; i < 4; ++i) {
      float vr[4], vi[4];
#pragma unroll
      for (int j = 0; j < 4; ++j) {
        vr[j] = fmaxf(accR[i][j] + brx[j], 0.f);
        vi[j] = fmaxf(accI[i][j] + bix[j], 0.f);
      }
      const size_t base = ((size_t)(t0 + tm * 4 + i) * U_ + u0 + un * 4) * 2;
      *(float4*)&xc[base + 0] = make_float4(vr[0], vi[0], vr[1], vi[1]);
      *(float4*)&xc[base + 4] = make_float4(vr[2], vi[2], vr[3], vi[3]);
    }
    // publish this tile: agent-visible release, one count per u-block
    __threadfence();
    __syncthreads();
    if (tid == 0)
      __hip_atomic_fetch_add(&flags[t0 >> 6], 1u, __ATOMIC_RELEASE,
                             __HIP_MEMORY_SCOPE_AGENT);
    return;
  }
  // ================= hopf role (R3 structure, PROVEN) ===================
  if (threadIdx.x >= 64) return;  // 1 wave per block; no barriers below
  __builtin_amdgcn_s_setprio(3);  // serial chain wins contested issue slots
  const int ub = bid & 31;
  const int osc = bid >> 5;
  const int u = ub * 64 + threadIdx.x;
  float phi = (osc ? phi2[u] : phi1[u]) * 0.1f;
  const float omega = osc ? om2[u] : om1[u];
  const uint32_t* __restrict__ dst = (osc ? d2c : d1c);
  const float dto = 0.01f * omega;
  float r = 1.0f;
  float c, s;
  __sincosf(phi, &s, &c);
  const uint32_t voffx = (uint32_t)u * 8u;  // byte offset into xc rows
  const uint32_t voffd = (uint32_t)u * 4u;  // byte offset into d rows

  constexpr int PF = 32;
  float2 bufA[PF], bufB[PF];
  // Prologue: rows 0..63 = tile 0; gate, then stage both groups.
  WAIT_TILE(0);
#pragma unroll
  for (int i = 0; i < PF; ++i) HOPF_LOAD(bufA, i, 0);
#pragma unroll
  for (int i = 0; i < PF; ++i) HOPF_LOAD(bufB, i, PF);
  VMWAIT(32);

  for (int t0 = 0; t0 < T_; t0 += 2 * PF) {
    // consume A (t0..t0+31): 32 stores
#pragma unroll
    for (int i = 0; i < PF; ++i) HOPF_STEP(bufA, i, t0);
    // gate + prefetch A <- t0+64 (tile t0/64+1; dummy wrap on tail)
    {
      int tp = t0 + 2 * PF;
      if (tp >= T_) tp = 0;
      WAIT_TILE(tp >> 6);  // RMW poll; drains vmcnt for its own result only
#pragma unroll
      for (int i = 0; i < PF; ++i) HOPF_LOAD(bufA, i, tp);
    }
    VMWAIT(63);
    // consume B (t0+32..t0+63)
#pragma unroll
    for (int i = 0; i < PF; ++i) HOPF_STEP(bufB, i, t0 + PF);
    // prefetch B <- t0+96 (same tile as A's prefetch; already gated)
    {
      int tp = t0 + 3 * PF;
      if (tp >= T_) tp = 0;
#pragma unroll
      for (int i = 0; i < PF; ++i) HOPF_LOAD(bufB, i, tp);
    }
    VMWAIT(63);
  }
  asm volatile("s_waitcnt vmcnt(0)");  // drain asm stores before endpgm
  __builtin_amdgcn_s_setprio(0);
}

// ---------------- Critic: value[t] ----------------
__global__ __launch_bounds__(256) void k_critic(
    const uint32_t* __restrict__ d1c, const float* __restrict__ cWr,
    const float* __restrict__ cWi, const float* __restrict__ cbr,
    const float* __restrict__ cbi, float* __restrict__ value) {
  const int t = blockIdx.x;
  const int tid = threadIdx.x;
  float vr = 0.f, vi = 0.f;
#pragma unroll
  for (int i = 0; i < 8; ++i) {
    const int uu = i * 256 + tid;
    const uint32_t p = d1c[(size_t)t * U_ + uu];
    const float dr = bflo(p), di = bfhi(p);
    const float wr = cWr[uu], wi = cWi[uu];
    vr = fmaf(dr, wr, fmaf(-di, wi, vr));
    vi = fmaf(dr, wi, fmaf(di, wr, vi));
  }
#pragma unroll
  for (int o = 32; o >= 1; o >>= 1) {
    vr += __shfl_xor(vr, o);
    vi += __shfl_xor(vi, o);
  }
  __shared__ float red[2][4];
  if ((tid & 63) == 0) { red[0][tid >> 6] = vr; red[1][tid >> 6] = vi; }
  __syncthreads();
  if (tid == 0) {
    const float r0 = red[0][0] + red[0][1] + red[0][2] + red[0][3] + cbr[0];
    const float i0 = red[1][0] + red[1][1] + red[1][2] + red[1][3] + cbi[0];
    value[t] = sqrtf(r0 * r0 + i0 * i0);
  }
}

// ---------------- lD1/lD2 ----------------
__global__ __launch_bounds__(256) void k_ld(const float* __restrict__ value,
                                            float* __restrict__ lD1,
                                            float* __restrict__ lD2) {
  const int t = blockIdx.x * 256 + threadIdx.x;
  const float v = value[t];
  const float pv = (t > 0) ? value[t - 1] : 0.f;
  const float x = 5.0f * (v - pv);
  const float sg = 1.0f / (1.0f + __expf(-x));
  lD1[t] = sg;
  lD2[t] = 1.0f - sg;
}

// ---------------- Phase-D GEMMs (K-split x4) ----------------
// tile 64t x 64a, 256 threads, thread 4t x 4a x 4 mats; K chunk 32.
__global__ __launch_bounds__(256) void k_gemmD(
    const uint32_t* __restrict__ d1c, const uint32_t* __restrict__ d2c,
    const float* __restrict__ dpWr, const float* __restrict__ dpWi,
    const float* __restrict__ ipWr, const float* __restrict__ ipWi,
    float* __restrict__ mpart) {
  __shared__ uint32_t d1T[32][68];
  __shared__ uint32_t d2T[32][68];
  __shared__ float w1r[32][68], w1i[32][68], w2r[32][68], w2i[32][68];
  const int tid = threadIdx.x;
  const int t0 = blockIdx.x * 64;
  const int ks = blockIdx.y;
  const int kb = ks * 512;
  const int an = tid & 15, tm = tid >> 4;
  const int lr = tid >> 3, lc = (tid & 7) * 4;
  float a1r[4][4] = {}, a1i[4][4] = {}, a2r[4][4] = {}, a2i[4][4] = {};
  for (int kc = 0; kc < 512; kc += 32) {
    __syncthreads();
#pragma unroll
    for (int p = 0; p < 2; ++p) {
      const int row = p * 32 + lr;
      const int col = kb + kc + lc;
      uint4 v1 = *(const uint4*)&d1c[(size_t)(t0 + row) * U_ + col];
      d1T[lc + 0][row] = v1.x; d1T[lc + 1][row] = v1.y;
      d1T[lc + 2][row] = v1.z; d1T[lc + 3][row] = v1.w;
      uint4 v2 = *(const uint4*)&d2c[(size_t)(t0 + row) * U_ + col];
      d2T[lc + 0][row] = v2.x; d2T[lc + 1][row] = v2.y;
      d2T[lc + 2][row] = v2.z; d2T[lc + 3][row] = v2.w;
      float4 f;
      f = *(const float4*)&dpWr[(size_t)row * U_ + col];
      w1r[lc + 0][row] = f.x; w1r[lc + 1][row] = f.y;
      w1r[lc + 2][row] = f.z; w1r[lc + 3][row] = f.w;
      f = *(const float4*)&dpWi[(size_t)row * U_ + col];
      w1i[lc + 0][row] = f.x; w1i[lc + 1][row] = f.y;
      w1i[lc + 2][row] = f.z; w1i[lc + 3][row] = f.w;
      f = *(const float4*)&ipWr[(size_t)row * U_ + col];
      w2r[lc + 0][row] = f.x; w2r[lc + 1][row] = f.y;
      w2r[lc + 2][row] = f.z; w2r[lc + 3][row] = f.w;
      f = *(const float4*)&ipWi[(size_t)row * U_ + col];
      w2i[lc + 0][row] = f.x; w2i[lc + 1][row] = f.y;
      w2i[lc + 2][row] = f.z; w2i[lc + 3][row] = f.w;
    }
    __syncthreads();
#pragma unroll
    for (int k = 0; k < 32; ++k) {
      const uint4 p1 = *(const uint4*)&d1T[k][tm * 4];
      const uint4 p2 = *(const uint4*)&d2T[k][tm * 4];
      const float4 q1r = *(const float4*)&w1r[k][an * 4];
      const float4 q1i = *(const float4*)&w1i[k][an * 4];
      const float4 q2r = *(const float4*)&w2r[k][an * 4];
      const float4 q2i = *(const float4*)&w2i[k][an * 4];
      const float d1r_[4] = {bflo(p1.x), bflo(p1.y), bflo(p1.z), bflo(p1.w)};
      const float d1i_[4] = {bfhi(p1.x), bfhi(p1.y), bfhi(p1.z), bfhi(p1.w)};
      const float d2r_[4] = {bflo(p2.x), bflo(p2.y), bflo(p2.z), bflo(p2.w)};
      const float d2i_[4] = {bfhi(p2.x), bfhi(p2.y), bfhi(p2.z), bfhi(p2.w)};
      const float u1r[4] = {q1r.x, q1r.y, q1r.z, q1r.w};
      const float u1i[4] = {q1i.x, q1i.y, q1i.z, q1i.w};
      const float u2r[4] = {q2r.x, q2r.y, q2r.z, q2r.w};
      const float u2i[4] = {q2i.x, q2i.y, q2i.z, q2i.w};
#pragma unroll
      for (int i = 0; i < 4; ++i)
#pragma unroll
        for (int j = 0; j < 4; ++j) {
          a1r[i][j] = fmaf(d1r_[i], u1r[j], fmaf(-d1i_[i], u1i[j], a1r[i][j]));
          a1i[i][j] = fmaf(d1r_[i], u1i[j], fmaf(d1i_[i], u1r[j], a1i[i][j]));
          a2r[i][j] = fmaf(d2r_[i], u2r[j], fmaf(-d2i_[i], u2i[j], a2r[i][j]));
          a2i[i][j] = fmaf(d2r_[i], u2i[j], fmaf(d2i_[i], u2r[j], a2i[i][j]));
        }
    }
  }
  const size_t MS = (size_t)T_ * A_;
#pragma unroll
  for (int i = 0; i < 4; ++i) {
    const size_t base = (size_t)(t0 + tm * 4 + i) * A_ + an * 4;
    *(float4*)&mpart[(size_t)(0 * 4 + ks) * MS + base] =
        make_float4(a1r[i][0], a1r[i][1], a1r[i][2], a1r[i][3]);
    *(float4*)&mpart[(size_t)(1 * 4 + ks) * MS + base] =
        make_float4(a1i[i][0], a1i[i][1], a1i[i][2], a1i[i][3]);
    *(float4*)&mpart[(size_t)(2 * 4 + ks) * MS + base] =
        make_float4(a2r[i][0], a2r[i][1], a2r[i][2], a2r[i][3]);
    *(float4*)&mpart[(size_t)(3 * 4 + ks) * MS + base] =
        make_float4(a2i[i][0], a2i[i][1], a2i[i][2], a2i[i][3]);
  }
}

// ---------------- Epilogue: partial-reduce + norm ----------------
__global__ __launch_bounds__(256) void k_epi(
    const float* __restrict__ mpart, const float* __restrict__ lD1,
    const float* __restrict__ lD2, const float* __restrict__ noise,
    const float* __restrict__ dpbr, const float* __restrict__ dpbi,
    const float* __restrict__ ipbr, const float* __restrict__ ipbi,
    float* __restrict__ nrm) {
  const size_t MS = (size_t)T_ * A_;
  const int gid = blockIdx.x * 256 + threadIdx.x;
  const size_t e0 = (size_t)gid * 4;
  const int t = (int)(e0 >> 6);
  const int a0 = (int)(e0 & 63);
  float m[4][4];
#pragma unroll
  for (int mi = 0; mi < 4; ++mi) {
    float4 acc = *(const float4*)&mpart[(size_t)(mi * 4 + 0) * MS + e0];
#pragma unroll
    for (int ksi = 1; ksi < 4; ++ksi) {
      const float4 v = *(const float4*)&mpart[(size_t)(mi * 4 + ksi) * MS + e0];
      acc.x += v.x; acc.y += v.y; acc.z += v.z; acc.w += v.w;
    }
    m[mi][0] = acc.x; m[mi][1] = acc.y; m[mi][2] = acc.z; m[mi][3] = acc.w;
  }
  const float l1 = lD1[t], l2 = lD2[t];
  const float4 nzv = *(const float4*)&noise[e0];
  const float nz[4] = {nzv.x, nzv.y, nzv.z, nzv.w};
  const float4 q1 = *(const float4*)&dpbr[a0];
  const float4 q2 = *(const float4*)&dpbi[a0];
  const float4 q3 = *(const float4*)&ipbr[a0];
  const float4 q4 = *(const float4*)&ipbi[a0];
  const float b1r[4] = {q1.x, q1.y, q1.z, q1.w};
  const float b1i[4] = {q2.x, q2.y, q2.z, q2.w};
  const float b2r[4] = {q3.x, q3.y, q3.z, q3.w};
  const float b2i[4] = {q4.x, q4.y, q4.z, q4.w};
  float res[4];
#pragma unroll
  for (int j = 0; j < 4; ++j) {
    const float dpr = fmaxf(fmaf(l1, m[0][j], b1r[j]), 0.f);
    const float dpi = fmaxf(fmaf(l1, m[1][j], b1i[j]), 0.f);
    const float ipr = fmaxf(fmaf(l2, m[2][j], b2r[j]), 0.f);
    const float ipi = fmaxf(fmaf(l2, m[3][j], b2i[j]), 0.f);
    const float nzs = l2 * (2.f * nz[j] - 1.f);
    const float dr = dpr - ipr - nzs;
    const float di = dpi - ipi;
    res[j] = sqrtf(dr * dr + di * di);
  }
  *(float4*)&nrm[e0] = make_float4(res[0], res[1], res[2], res[3]);
}

// ---------------- Scan + softmax + outputs (parallel, 3 kernels) ----------
// chunk = 64 t-steps; 64 chunks. (Summation order proven passing.)
__global__ __launch_bounds__(64) void k_scan_part(const float* __restrict__ nrm,
                                                  float* __restrict__ csum) {
  const int c = blockIdx.x;
  const int a = threadIdx.x;
  const int tb = c * 64;
  float run = 0.f;
  for (int i = 0; i < 64; ++i) run += nrm[(size_t)(tb + i) * 64 + a];
  csum[c * 64 + a] = run;
}

__global__ __launch_bounds__(64) void k_scan_mid(const float* __restrict__ csum,
                                                 const float* __restrict__ value,
                                                 float* __restrict__ coff,
                                                 float* __restrict__ out) {
  const int a = threadIdx.x;
  float acc = 0.f;
#pragma unroll
  for (int cc = 0; cc < 64; ++cc) {
    coff[cc * 64 + a] = acc;
    acc += csum[cc * 64 + a];
  }
  const float g = 0.01f * acc;
  float mx = g;
#pragma unroll
  for (int o = 32; o >= 1; o >>= 1) mx = fmaxf(mx, __shfl_xor(mx, o));
  const float e = __expf(g - mx);
  float sm = e;
#pragma unroll
  for (int o = 32; o >= 1; o >>= 1) sm += __shfl_xor(sm, o);
  out[a] = e / sm;
  if (a == 0) out[64] = value[T_ - 1];
}

__global__ __launch_bounds__(64) void k_scan_out(const float* __restrict__ nrm,
                                                 const float* __restrict__ coff,
                                                 float* __restrict__ out) {
  const int c = blockIdx.x;
  const int a = threadIdx.x;
  const int tb = c * 64;
  float off = coff[c * 64 + a];
  float* o65 = out + 65;
  for (int i = 0; i < 64; ++i) {
    off += nrm[(size_t)(tb + i) * 64 + a];
    o65[(size_t)(tb + i) * 64 + a] = 0.01f * off;
  }
}

extern "C" void kernel_launch(void* const* d_in, const int* in_sizes, int n_in,
                              void* d_out, int out_size, void* d_ws,
                              size_t ws_size, hipStream_t stream) {
  const float* state = (const float*)d_in[0];
  const float* phi1 = (const float*)d_in[1];
  const float* phi2 = (const float*)d_in[2];
  const float* noise = (const float*)d_in[3];
  const float* om1 = (const float*)d_in[4];
  const float* om2 = (const float*)d_in[5];
  const float* l1Wr = (const float*)d_in[6];
  const float* l1Wi = (const float*)d_in[7];
  const float* l1br = (const float*)d_in[8];
  const float* l1bi = (const float*)d_in[9];
  const float* dpWr = (const float*)d_in[10];
  const float* dpWi = (const float*)d_in[11];
  const float* dpbr = (const float*)d_in[12];
  const float* dpbi = (const float*)d_in[13];
  const float* ipWr = (const float*)d_in[14];
  const float* ipWi = (const float*)d_in[15];
  const float* ipbr = (const float*)d_in[16];
  const float* ipbi = (const float*)d_in[17];
  const float* cWr = (const float*)d_in[18];
  const float* cWi = (const float*)d_in[19];
  const float* cbr = (const float*)d_in[20];
  const float* cbi = (const float*)d_in[21];
  float* out = (float*)d_out;

  // Workspace layout (overlapped; 128 MB total):
  //   [0,64M)   xc plane (fp32 r,i interleaved) -- dead after fused; reused
  //   [64M,96M) d1c (bf16 pairs)
  //   [96M,128M) d2c (bf16 pairs)
  //   reuse of [0,64M) after fused kernel:
  //     [0,16M)        mpart
  //     [16M,17M)      nrm
  //     [17M, +16K)    value
  //     [17M+16K..]    lD1, lD2, csum, coff
  // flags: first 256B of d_out (zeroed below; overwritten by k_scan_mid).
  char* ws = (char*)d_ws;
  float* xc = (float*)(ws + (size_t)0);
  uint32_t* d1c = (uint32_t*)(ws + (size_t)67108864);
  uint32_t* d2c = (uint32_t*)(ws + (size_t)100663296);
  float* mpart = (float*)(ws + (size_t)0);
  float* nrm = (float*)(ws + (size_t)16777216);
  float* value = (float*)(ws + (size_t)17825792);
  float* lD1 = (float*)(ws + (size_t)17825792 + 16384);
  float* lD2 = (float*)(ws + (size_t)17825792 + 32768);
  float* csum = (float*)(ws + (size_t)17825792 + 49152);
  float* coff = (float*)(ws + (size_t)17825792 + 65536);
  uint32_t* flags = (uint32_t*)out;

  hipMemsetAsync(out, 0, 256, stream);  // zero tile flags (stream-ordered)
  k_g1hopf<<<64 + (T_ / 64) * (U_ / 64), 256, 0, stream>>>(
      state, l1Wr, l1Wi, l1br, l1bi, phi1, phi2, om1, om2, xc, d1c, d2c,
      flags);
  k_critic<<<T_, 256, 0, stream>>>(d1c, cWr, cWi, cbr, cbi, value);
  k_ld<<<T_ / 256, 256, 0, stream>>>(value, lD1, lD2);
  k_gemmD<<<dim3(T_ / 64, 4), 256, 0, stream>>>(d1c, d2c, dpWr, dpWi, ipWr,
                                                ipWi, mpart);
  k_epi<<<256, 256, 0, stream>>>(mpart, lD1, lD2, noise, dpbr, dpbi, ipbr,
                                 ipbi, nrm);
  k_scan_part<<<64, 64, 0, stream>>>(nrm, csum);
  k_scan_mid<<<1, 64, 0, stream>>>(csum, value, coff, out);
  k_scan_out<<<64, 64, 0, stream>>>(nrm, coff, out);
}

// Round 14
// 504.500 us; speedup vs baseline: 1.5259x; 1.4682x over previous
//
#include <hip/hip_runtime.h>
#include <hip/hip_bf16.h>
#include <stdint.h>

// Pipeline:
//   k_g1hopf: FUSED producer/consumer — blocks 0..63 run the Hopf chains,
//             blocks 64..2111 run gemm1 t-tiles; per-t-tile device-scope
//             flags (in d_out scratch) let hopf start as tiles land.
//   k_critic: value[t] = |c-linear(d1[t])|
//   k_ld    : lD1/lD2[t] = sigmoid(+-5*(value[t]-value[t-1]))
//   k_gemmD : M1r/M1i/M2r/M2i partials, K-split x4
//   k_epi   : reduce partials + lD scaling + bias + relu + noise + norm -> nrm
//   k_scan_part/mid/out : gpi = 0.01*cumsum(nrm), softmax, outputs
//
// Ledger (razor-margin test: passing absmax 1.25 vs threshold 1.27):
//   R3 hopf: 212us PASSED; numerics BIT-FROZEN on gemm1->hopf path.
//   R10 = serial gemm1+hopf + split scan: 576us PASSED (best proven).
//   R11 fusion v1 (ACQUIRE poll): PASSED but fused kernel 578us.
//   R12 fusion v2 (RELAXED RMW poll + setprio3): 557us — both fixes no-ops
//     => mechanism common to R11/R12: producer __threadfence lowers to
//     buffer_wbl2 sc1 (FULL XCD-L2 dirty writeback, required for cross-XCD
//     release on non-coherent L2s) x 2048 producer blocks + another wbl2
//     in the RELEASE fetch_add => device-wide ~1.8x slowdown; fits
//     WRITE_SIZE inflation 154 vs ~130MB.
//   R13: same theory; DNC — float4 (class type) passed indirectly to asm.
//   R14 (this): identical logic; asm operands fixed to ext_vector float4
//     (first-class vector => legal "v" 4-reg tuple). xc stores carry sc1
//     (complete at agent coherence point / LLC — no dirty L2 line), tail =
//     s_waitcnt vmcnt(0) -> __syncthreads -> tid0 RELAXED fetch_add (no
//     fence lowering). Ordering structural: flag RMW issued only after
//     stores COMPLETED at the coherent point. Stored bits identical.
//   Fallback (pre-committed): fused still >450us => abandon fusion, revert
//     to R10 and tune gemmD/critic.

#define T_ 4096
#define D_ 256
#define U_ 2048
#define A_ 64

typedef float f32x4 __attribute__((ext_vector_type(4)));

__device__ __forceinline__ uint32_t pack2(float lo, float hi) {
  __hip_bfloat16 l = __float2bfloat16(lo);
  __hip_bfloat16 h = __float2bfloat16(hi);
  uint16_t lu, hu;
  __builtin_memcpy(&lu, &l, 2);
  __builtin_memcpy(&hu, &h, 2);
  return (uint32_t)lu | ((uint32_t)hu << 16);
}
__device__ __forceinline__ float bflo(uint32_t p) { return __uint_as_float(p << 16); }
__device__ __forceinline__ float bfhi(uint32_t p) { return __uint_as_float(p & 0xffff0000u); }

// ---------------- Hopf step/load macros (R3 structure, PROVEN) -----------
#define HOPF_LOAD(BUF, i, tbase)                                            \
  do {                                                                      \
    const float* bx_ = xc + (size_t)((tbase) + (i)) * (U_ * 2);             \
    asm volatile("global_load_dwordx2 %0, %1, %2"                           \
                 : "=v"(BUF[i])                                             \
                 : "v"(voffx), "s"(bx_));                                   \
  } while (0)

#define HOPF_STEP(BUF, i, tb)                                               \
  do {                                                                      \
    const float xr_ = BUF[i].x, xi_ = BUF[i].y;                             \
    const float f_ = fmaf(xr_, c, xi_ * s);                                 \
    const float g_ = fmaf(xi_, c, -(xr_ * s));                              \
    const float rn_ = fmaf(0.01f, fmaf(r, fmaf(-r, r, 1.0f), f_), r);       \
    const float rinv_ = __builtin_amdgcn_rcpf(fmaxf(r, 1e-6f));             \
    const float phin_ = fmaf(0.01f, g_ * rinv_, phi + dto);                 \
    float cn_, sn_;                                                         \
    __sincosf(phin_, &sn_, &cn_);                                           \
    uint32_t pk_;                                                           \
    asm("v_cvt_pk_bf16_f32 %0, %1, %2"                                     \
        : "=v"(pk_)                                                         \
        : "v"(rn_ * cn_), "v"(rn_ * sn_));                                  \
    const uint32_t* bd_ = dst + (size_t)((tb) + (i)) * U_;                  \
    asm volatile("global_store_dword %0, %1, %2" ::"v"(voffd), "v"(pk_),    \
                 "s"(bd_));                                                  \
    r = rn_; phi = phin_; c = cn_; s = sn_;                                 \
  } while (0)

#define VMWAIT(N)                                  \
  asm volatile("s_waitcnt vmcnt(" #N ")");         \
  __builtin_amdgcn_sched_barrier(0)

// consumer-side tile gate: RELAXED RMW poll (coherent-point read, no
// cache-maintenance lowering). Prefetch runs 64 steps ahead of consume,
// so in steady state this is one satisfied RMW per iteration.
#define WAIT_TILE(tt)                                                       \
  do {                                                                      \
    while (__hip_atomic_fetch_add(&flags[tt], 0u, __ATOMIC_RELAXED,         \
                                  __HIP_MEMORY_SCOPE_AGENT) < 32u)          \
      __builtin_amdgcn_s_sleep(8);                                          \
    __builtin_amdgcn_sched_barrier(0);                                      \
  } while (0)

// ---------------- FUSED gemm1 + hopf ----------------
// grid 2112 x 256: blocks 0..63 hopf (threads 0..63 active), 64..2111 gemm1.
// gemm1 tile map: gb = bid-64; t_tile = gb>>5, u_tile = gb&31  (u fastest,
// so in-order dispatch completes t-tiles in ascending order).
__global__ __launch_bounds__(256) void k_g1hopf(
    const float* __restrict__ S, const float* __restrict__ Wr,
    const float* __restrict__ Wi, const float* __restrict__ br,
    const float* __restrict__ bi, const float* __restrict__ phi1,
    const float* __restrict__ phi2, const float* __restrict__ om1,
    const float* __restrict__ om2, float* __restrict__ xc,
    uint32_t* __restrict__ d1c, uint32_t* __restrict__ d2c,
    uint32_t* __restrict__ flags) {
  const int bid = blockIdx.x;
  if (bid >= 64) {
    // ================= gemm1 role (NUMERICS FROZEN, byte-identical) =====
    __shared__ float sT[32][68];
    __shared__ float wrT[32][68];
    __shared__ float wiT[32][68];
    const int tid = threadIdx.x;
    const int gb = bid - 64;
    const int t0 = (gb >> 5) * 64;
    const int u0 = (gb & 31) * 64;
    const int un = tid & 15, tm = tid >> 4;
    const int lr = tid >> 3;        // 0..31
    const int lc = (tid & 7) * 4;   // 0..28
    float accR[4][4] = {}, accI[4][4] = {};
    for (int k0 = 0; k0 < D_; k0 += 32) {
      __syncthreads();
#pragma unroll
      for (int p = 0; p < 2; ++p) {
        const int row = p * 32 + lr;
        float4 v = *(const float4*)&S[(size_t)(t0 + row) * D_ + k0 + lc];
        sT[lc + 0][row] = v.x; sT[lc + 1][row] = v.y;
        sT[lc + 2][row] = v.z; sT[lc + 3][row] = v.w;
        float4 a = *(const float4*)&Wr[(size_t)(u0 + row) * D_ + k0 + lc];
        wrT[lc + 0][row] = a.x; wrT[lc + 1][row] = a.y;
        wrT[lc + 2][row] = a.z; wrT[lc + 3][row] = a.w;
        float4 b = *(const float4*)&Wi[(size_t)(u0 + row) * D_ + k0 + lc];
        wiT[lc + 0][row] = b.x; wiT[lc + 1][row] = b.y;
        wiT[lc + 2][row] = b.z; wiT[lc + 3][row] = b.w;
      }
      __syncthreads();
#pragma unroll
      for (int k = 0; k < 32; ++k) {
        const float4 sv = *(const float4*)&sT[k][tm * 4];
        const float4 ar = *(const float4*)&wrT[k][un * 4];
        const float4 ai = *(const float4*)&wiT[k][un * 4];
        const float ss[4] = {sv.x, sv.y, sv.z, sv.w};
        const float wd[4] = {ar.x - ai.x, ar.y - ai.y, ar.z - ai.z, ar.w - ai.w};
        const float wm[4] = {ar.x + ai.x, ar.y + ai.y, ar.z + ai.z, ar.w + ai.w};
#pragma unroll
        for (int i = 0; i < 4; ++i)
#pragma unroll
          for (int j = 0; j < 4; ++j) {
            accR[i][j] = fmaf(ss[i], wd[j], accR[i][j]);
            accI[i][j] = fmaf(ss[i], wm[j], accI[i][j]);
          }
      }
    }
    const float4 brv = *(const float4*)&br[u0 + un * 4];
    const float4 biv = *(const float4*)&bi[u0 + un * 4];
    const float brx[4] = {brv.x, brv.y, brv.z, brv.w};
    const float bix[4] = {biv.x, biv.y, biv.z, biv.w};
#pragma unroll
    for (int i = 0; i < 4; ++i) {
      float vr[4], vi[4];
#pragma unroll
      for (int j = 0; j < 4; ++j) {
        vr[j] = fmaxf(accR[i][j] + brx[j], 0.f);
        vi[j] = fmaxf(accI[i][j] + bix[j], 0.f);
      }
      const size_t base = ((size_t)(t0 + tm * 4 + i) * U_ + u0 + un * 4) * 2;
      f32x4 lo = {vr[0], vi[0], vr[1], vi[1]};
      f32x4 hi = {vr[2], vi[2], vr[3], vi[3]};
      float* p0 = &xc[base];
      float* p1 = &xc[base + 4];
      // sc1 = complete at agent coherence point (LLC); no dirty XCD-L2 line,
      // so NO bulk wbl2 fence is needed to publish. Bits identical.
      asm volatile("global_store_dwordx4 %0, %1, off sc1" ::"v"(p0), "v"(lo)
                   : "memory");
      asm volatile("global_store_dwordx4 %0, %1, off sc1" ::"v"(p1), "v"(hi)
                   : "memory");
    }
    // publish: stores COMPLETE at coherent point, then flag add (RELAXED —
    // no wbl2 lowering; ordering is structural via the completed waitcnt).
    asm volatile("s_waitcnt vmcnt(0)");
    __syncthreads();
    if (tid == 0)
      __hip_atomic_fetch_add(&flags[t0 >> 6], 1u, __ATOMIC_RELAXED,
                             __HIP_MEMORY_SCOPE_AGENT);
    return;
  }
  // ================= hopf role (R3 structure, PROVEN) ===================
  if (threadIdx.x >= 64) return;  // 1 wave per block; no barriers below
  __builtin_amdgcn_s_setprio(3);  // serial chain wins contested issue slots
  const int ub = bid & 31;
  const int osc = bid >> 5;
  const int u = ub * 64 + threadIdx.x;
  float phi = (osc ? phi2[u] : phi1[u]) * 0.1f;
  const float omega = osc ? om2[u] : om1[u];
  const uint32_t* __restrict__ dst = (osc ? d2c : d1c);
  const float dto = 0.01f * omega;
  float r = 1.0f;
  float c, s;
  __sincosf(phi, &s, &c);
  const uint32_t voffx = (uint32_t)u * 8u;  // byte offset into xc rows
  const uint32_t voffd = (uint32_t)u * 4u;  // byte offset into d rows

  constexpr int PF = 32;
  float2 bufA[PF], bufB[PF];
  // Prologue: rows 0..63 = tile 0; gate, then stage both groups.
  WAIT_TILE(0);
#pragma unroll
  for (int i = 0; i < PF; ++i) HOPF_LOAD(bufA, i, 0);
#pragma unroll
  for (int i = 0; i < PF; ++i) HOPF_LOAD(bufB, i, PF);
  VMWAIT(32);

  for (int t0 = 0; t0 < T_; t0 += 2 * PF) {
    // consume A (t0..t0+31): 32 stores
#pragma unroll
    for (int i = 0; i < PF; ++i) HOPF_STEP(bufA, i, t0);
    // gate + prefetch A <- t0+64 (tile t0/64+1; dummy wrap on tail)
    {
      int tp = t0 + 2 * PF;
      if (tp >= T_) tp = 0;
      WAIT_TILE(tp >> 6);  // RMW poll; waits only its own result
#pragma unroll
      for (int i = 0; i < PF; ++i) HOPF_LOAD(bufA, i, tp);
    }
    VMWAIT(63);
    // consume B (t0+32..t0+63)
#pragma unroll
    for (int i = 0; i < PF; ++i) HOPF_STEP(bufB, i, t0 + PF);
    // prefetch B <- t0+96 (same tile as A's prefetch; already gated)
    {
      int tp = t0 + 3 * PF;
      if (tp >= T_) tp = 0;
#pragma unroll
      for (int i = 0; i < PF; ++i) HOPF_LOAD(bufB, i, tp);
    }
    VMWAIT(63);
  }
  asm volatile("s_waitcnt vmcnt(0)");  // drain asm stores before endpgm
  __builtin_amdgcn_s_setprio(0);
}

// ---------------- Critic: value[t] ----------------
__global__ __launch_bounds__(256) void k_critic(
    const uint32_t* __restrict__ d1c, const float* __restrict__ cWr,
    const float* __restrict__ cWi, const float* __restrict__ cbr,
    const float* __restrict__ cbi, float* __restrict__ value) {
  const int t = blockIdx.x;
  const int tid = threadIdx.x;
  float vr = 0.f, vi = 0.f;
#pragma unroll
  for (int i = 0; i < 8; ++i) {
    const int uu = i * 256 + tid;
    const uint32_t p = d1c[(size_t)t * U_ + uu];
    const float dr = bflo(p), di = bfhi(p);
    const float wr = cWr[uu], wi = cWi[uu];
    vr = fmaf(dr, wr, fmaf(-di, wi, vr));
    vi = fmaf(dr, wi, fmaf(di, wr, vi));
  }
#pragma unroll
  for (int o = 32; o >= 1; o >>= 1) {
    vr += __shfl_xor(vr, o);
    vi += __shfl_xor(vi, o);
  }
  __shared__ float red[2][4];
  if ((tid & 63) == 0) { red[0][tid >> 6] = vr; red[1][tid >> 6] = vi; }
  __syncthreads();
  if (tid == 0) {
    const float r0 = red[0][0] + red[0][1] + red[0][2] + red[0][3] + cbr[0];
    const float i0 = red[1][0] + red[1][1] + red[1][2] + red[1][3] + cbi[0];
    value[t] = sqrtf(r0 * r0 + i0 * i0);
  }
}

// ---------------- lD1/lD2 ----------------
__global__ __launch_bounds__(256) void k_ld(const float* __restrict__ value,
                                            float* __restrict__ lD1,
                                            float* __restrict__ lD2) {
  const int t = blockIdx.x * 256 + threadIdx.x;
  const float v = value[t];
  const float pv = (t > 0) ? value[t - 1] : 0.f;
  const float x = 5.0f * (v - pv);
  const float sg = 1.0f / (1.0f + __expf(-x));
  lD1[t] = sg;
  lD2[t] = 1.0f - sg;
}

// ---------------- Phase-D GEMMs (K-split x4) ----------------
// tile 64t x 64a, 256 threads, thread 4t x 4a x 4 mats; K chunk 32.
__global__ __launch_bounds__(256) void k_gemmD(
    const uint32_t* __restrict__ d1c, const uint32_t* __restrict__ d2c,
    const float* __restrict__ dpWr, const float* __restrict__ dpWi,
    const float* __restrict__ ipWr, const float* __restrict__ ipWi,
    float* __restrict__ mpart) {
  __shared__ uint32_t d1T[32][68];
  __shared__ uint32_t d2T[32][68];
  __shared__ float w1r[32][68], w1i[32][68], w2r[32][68], w2i[32][68];
  const int tid = threadIdx.x;
  const int t0 = blockIdx.x * 64;
  const int ks = blockIdx.y;
  const int kb = ks * 512;
  const int an = tid & 15, tm = tid >> 4;
  const int lr = tid >> 3, lc = (tid & 7) * 4;
  float a1r[4][4] = {}, a1i[4][4] = {}, a2r[4][4] = {}, a2i[4][4] = {};
  for (int kc = 0; kc < 512; kc += 32) {
    __syncthreads();
#pragma unroll
    for (int p = 0; p < 2; ++p) {
      const int row = p * 32 + lr;
      const int col = kb + kc + lc;
      uint4 v1 = *(const uint4*)&d1c[(size_t)(t0 + row) * U_ + col];
      d1T[lc + 0][row] = v1.x; d1T[lc + 1][row] = v1.y;
      d1T[lc + 2][row] = v1.z; d1T[lc + 3][row] = v1.w;
      uint4 v2 = *(const uint4*)&d2c[(size_t)(t0 + row) * U_ + col];
      d2T[lc + 0][row] = v2.x; d2T[lc + 1][row] = v2.y;
      d2T[lc + 2][row] = v2.z; d2T[lc + 3][row] = v2.w;
      float4 f;
      f = *(const float4*)&dpWr[(size_t)row * U_ + col];
      w1r[lc + 0][row] = f.x; w1r[lc + 1][row] = f.y;
      w1r[lc + 2][row] = f.z; w1r[lc + 3][row] = f.w;
      f = *(const float4*)&dpWi[(size_t)row * U_ + col];
      w1i[lc + 0][row] = f.x; w1i[lc + 1][row] = f.y;
      w1i[lc + 2][row] = f.z; w1i[lc + 3][row] = f.w;
      f = *(const float4*)&ipWr[(size_t)row * U_ + col];
      w2r[lc + 0][row] = f.x; w2r[lc + 1][row] = f.y;
      w2r[lc + 2][row] = f.z; w2r[lc + 3][row] = f.w;
      f = *(const float4*)&ipWi[(size_t)row * U_ + col];
      w2i[lc + 0][row] = f.x; w2i[lc + 1][row] = f.y;
      w2i[lc + 2][row] = f.z; w2i[lc + 3][row] = f.w;
    }
    __syncthreads();
#pragma unroll
    for (int k = 0; k < 32; ++k) {
      const uint4 p1 = *(const uint4*)&d1T[k][tm * 4];
      const uint4 p2 = *(const uint4*)&d2T[k][tm * 4];
      const float4 q1r = *(const float4*)&w1r[k][an * 4];
      const float4 q1i = *(const float4*)&w1i[k][an * 4];
      const float4 q2r = *(const float4*)&w2r[k][an * 4];
      const float4 q2i = *(const float4*)&w2i[k][an * 4];
      const float d1r_[4] = {bflo(p1.x), bflo(p1.y), bflo(p1.z), bflo(p1.w)};
      const float d1i_[4] = {bfhi(p1.x), bfhi(p1.y), bfhi(p1.z), bfhi(p1.w)};
      const float d2r_[4] = {bflo(p2.x), bflo(p2.y), bflo(p2.z), bflo(p2.w)};
      const float d2i_[4] = {bfhi(p2.x), bfhi(p2.y), bfhi(p2.z), bfhi(p2.w)};
      const float u1r[4] = {q1r.x, q1r.y, q1r.z, q1r.w};
      const float u1i[4] = {q1i.x, q1i.y, q1i.z, q1i.w};
      const float u2r[4] = {q2r.x, q2r.y, q2r.z, q2r.w};
      const float u2i[4] = {q2i.x, q2i.y, q2i.z, q2i.w};
#pragma unroll
      for (int i = 0; i < 4; ++i)
#pragma unroll
        for (int j = 0; j < 4; ++j) {
          a1r[i][j] = fmaf(d1r_[i], u1r[j], fmaf(-d1i_[i], u1i[j], a1r[i][j]));
          a1i[i][j] = fmaf(d1r_[i], u1i[j], fmaf(d1i_[i], u1r[j], a1i[i][j]));
          a2r[i][j] = fmaf(d2r_[i], u2r[j], fmaf(-d2i_[i], u2i[j], a2r[i][j]));
          a2i[i][j] = fmaf(d2r_[i], u2i[j], fmaf(d2i_[i], u2r[j], a2i[i][j]));
        }
    }
  }
  const size_t MS = (size_t)T_ * A_;
#pragma unroll
  for (int i = 0; i < 4; ++i) {
    const size_t base = (size_t)(t0 + tm * 4 + i) * A_ + an * 4;
    *(float4*)&mpart[(size_t)(0 * 4 + ks) * MS + base] =
        make_float4(a1r[i][0], a1r[i][1], a1r[i][2], a1r[i][3]);
    *(float4*)&mpart[(size_t)(1 * 4 + ks) * MS + base] =
        make_float4(a1i[i][0], a1i[i][1], a1i[i][2], a1i[i][3]);
    *(float4*)&mpart[(size_t)(2 * 4 + ks) * MS + base] =
        make_float4(a2r[i][0], a2r[i][1], a2r[i][2], a2r[i][3]);
    *(float4*)&mpart[(size_t)(3 * 4 + ks) * MS + base] =
        make_float4(a2i[i][0], a2i[i][1], a2i[i][2], a2i[i][3]);
  }
}

// ---------------- Epilogue: partial-reduce + norm ----------------
__global__ __launch_bounds__(256) void k_epi(
    const float* __restrict__ mpart, const float* __restrict__ lD1,
    const float* __restrict__ lD2, const float* __restrict__ noise,
    const float* __restrict__ dpbr, const float* __restrict__ dpbi,
    const float* __restrict__ ipbr, const float* __restrict__ ipbi,
    float* __restrict__ nrm) {
  const size_t MS = (size_t)T_ * A_;
  const int gid = blockIdx.x * 256 + threadIdx.x;
  const size_t e0 = (size_t)gid * 4;
  const int t = (int)(e0 >> 6);
  const int a0 = (int)(e0 & 63);
  float m[4][4];
#pragma unroll
  for (int mi = 0; mi < 4; ++mi) {
    float4 acc = *(const float4*)&mpart[(size_t)(mi * 4 + 0) * MS + e0];
#pragma unroll
    for (int ksi = 1; ksi < 4; ++ksi) {
      const float4 v = *(const float4*)&mpart[(size_t)(mi * 4 + ksi) * MS + e0];
      acc.x += v.x; acc.y += v.y; acc.z += v.z; acc.w += v.w;
    }
    m[mi][0] = acc.x; m[mi][1] = acc.y; m[mi][2] = acc.z; m[mi][3] = acc.w;
  }
  const float l1 = lD1[t], l2 = lD2[t];
  const float4 nzv = *(const float4*)&noise[e0];
  const float nz[4] = {nzv.x, nzv.y, nzv.z, nzv.w};
  const float4 q1 = *(const float4*)&dpbr[a0];
  const float4 q2 = *(const float4*)&dpbi[a0];
  const float4 q3 = *(const float4*)&ipbr[a0];
  const float4 q4 = *(const float4*)&ipbi[a0];
  const float b1r[4] = {q1.x, q1.y, q1.z, q1.w};
  const float b1i[4] = {q2.x, q2.y, q2.z, q2.w};
  const float b2r[4] = {q3.x, q3.y, q3.z, q3.w};
  const float b2i[4] = {q4.x, q4.y, q4.z, q4.w};
  float res[4];
#pragma unroll
  for (int j = 0; j < 4; ++j) {
    const float dpr = fmaxf(fmaf(l1, m[0][j], b1r[j]), 0.f);
    const float dpi = fmaxf(fmaf(l1, m[1][j], b1i[j]), 0.f);
    const float ipr = fmaxf(fmaf(l2, m[2][j], b2r[j]), 0.f);
    const float ipi = fmaxf(fmaf(l2, m[3][j], b2i[j]), 0.f);
    const float nzs = l2 * (2.f * nz[j] - 1.f);
    const float dr = dpr - ipr - nzs;
    const float di = dpi - ipi;
    res[j] = sqrtf(dr * dr + di * di);
  }
  *(float4*)&nrm[e0] = make_float4(res[0], res[1], res[2], res[3]);
}

// ---------------- Scan + softmax + outputs (parallel, 3 kernels) ----------
// chunk = 64 t-steps; 64 chunks. (Summation order proven passing.)
__global__ __launch_bounds__(64) void k_scan_part(const float* __restrict__ nrm,
                                                  float* __restrict__ csum) {
  const int c = blockIdx.x;
  const int a = threadIdx.x;
  const int tb = c * 64;
  float run = 0.f;
  for (int i = 0; i < 64; ++i) run += nrm[(size_t)(tb + i) * 64 + a];
  csum[c * 64 + a] = run;
}

__global__ __launch_bounds__(64) void k_scan_mid(const float* __restrict__ csum,
                                                 const float* __restrict__ value,
                                                 float* __restrict__ coff,
                                                 float* __restrict__ out) {
  const int a = threadIdx.x;
  float acc = 0.f;
#pragma unroll
  for (int cc = 0; cc < 64; ++cc) {
    coff[cc * 64 + a] = acc;
    acc += csum[cc * 64 + a];
  }
  const float g = 0.01f * acc;
  float mx = g;
#pragma unroll
  for (int o = 32; o >= 1; o >>= 1) mx = fmaxf(mx, __shfl_xor(mx, o));
  const float e = __expf(g - mx);
  float sm = e;
#pragma unroll
  for (int o = 32; o >= 1; o >>= 1) sm += __shfl_xor(sm, o);
  out[a] = e / sm;
  if (a == 0) out[64] = value[T_ - 1];
}

__global__ __launch_bounds__(64) void k_scan_out(const float* __restrict__ nrm,
                                                 const float* __restrict__ coff,
                                                 float* __restrict__ out) {
  const int c = blockIdx.x;
  const int a = threadIdx.x;
  const int tb = c * 64;
  float off = coff[c * 64 + a];
  float* o65 = out + 65;
  for (int i = 0; i < 64; ++i) {
    off += nrm[(size_t)(tb + i) * 64 + a];
    o65[(size_t)(tb + i) * 64 + a] = 0.01f * off;
  }
}

extern "C" void kernel_launch(void* const* d_in, const int* in_sizes, int n_in,
                              void* d_out, int out_size, void* d_ws,
                              size_t ws_size, hipStream_t stream) {
  const float* state = (const float*)d_in[0];
  const float* phi1 = (const float*)d_in[1];
  const float* phi2 = (const float*)d_in[2];
  const float* noise = (const float*)d_in[3];
  const float* om1 = (const float*)d_in[4];
  const float* om2 = (const float*)d_in[5];
  const float* l1Wr = (const float*)d_in[6];
  const float* l1Wi = (const float*)d_in[7];
  const float* l1br = (const float*)d_in[8];
  const float* l1bi = (const float*)d_in[9];
  const float* dpWr = (const float*)d_in[10];
  const float* dpWi = (const float*)d_in[11];
  const float* dpbr = (const float*)d_in[12];
  const float* dpbi = (const float*)d_in[13];
  const float* ipWr = (const float*)d_in[14];
  const float* ipWi = (const float*)d_in[15];
  const float* ipbr = (const float*)d_in[16];
  const float* ipbi = (const float*)d_in[17];
  const float* cWr = (const float*)d_in[18];
  const float* cWi = (const float*)d_in[19];
  const float* cbr = (const float*)d_in[20];
  const float* cbi = (const float*)d_in[21];
  float* out = (float*)d_out;

  // Workspace layout (overlapped; 128 MB total):
  //   [0,64M)   xc plane (fp32 r,i interleaved) -- dead after fused; reused
  //   [64M,96M) d1c (bf16 pairs)
  //   [96M,128M) d2c (bf16 pairs)
  //   reuse of [0,64M) after fused kernel:
  //     [0,16M)        mpart
  //     [16M,17M)      nrm
  //     [17M, +16K)    value
  //     [17M+16K..]    lD1, lD2, csum, coff
  // flags: first 256B of d_out (zeroed below; overwritten by k_scan_mid).
  char* ws = (char*)d_ws;
  float* xc = (float*)(ws + (size_t)0);
  uint32_t* d1c = (uint32_t*)(ws + (size_t)67108864);
  uint32_t* d2c = (uint32_t*)(ws + (size_t)100663296);
  float* mpart = (float*)(ws + (size_t)0);
  float* nrm = (float*)(ws + (size_t)16777216);
  float* value = (float*)(ws + (size_t)17825792);
  float* lD1 = (float*)(ws + (size_t)17825792 + 16384);
  float* lD2 = (float*)(ws + (size_t)17825792 + 32768);
  float* csum = (float*)(ws + (size_t)17825792 + 49152);
  float* coff = (float*)(ws + (size_t)17825792 + 65536);
  uint32_t* flags = (uint32_t*)out;

  hipMemsetAsync(out, 0, 256, stream);  // zero tile flags (stream-ordered)
  k_g1hopf<<<64 + (T_ / 64) * (U_ / 64), 256, 0, stream>>>(
      state, l1Wr, l1Wi, l1br, l1bi, phi1, phi2, om1, om2, xc, d1c, d2c,
      flags);
  k_critic<<<T_, 256, 0, stream>>>(d1c, cWr, cWi, cbr, cbi, value);
  k_ld<<<T_ / 256, 256, 0, stream>>>(value, lD1, lD2);
  k_gemmD<<<dim3(T_ / 64, 4), 256, 0, stream>>>(d1c, d2c, dpWr, dpWi, ipWr,
                                                ipWi, mpart);
  k_epi<<<256, 256, 0, stream>>>(mpart, lD1, lD2, noise, dpbr, dpbi, ipbr,
                                 ipbi, nrm);
  k_scan_part<<<64, 64, 0, stream>>>(nrm, csum);
  k_scan_mid<<<1, 64, 0, stream>>>(csum, value, coff, out);
  k_scan_out<<<64, 64, 0, stream>>>(nrm, coff, out);
}